// Round 1
// baseline (243.779 us; speedup 1.0000x reference)
//
#include <hip/hip_runtime.h>
#include <math.h>

#define NTOK   16384
#define DIM    4096
#define NE     64
#define TOPK   8
#define TB     32          // tokens per block
#define DC     64          // d-chunk staged in LDS
#define XS_STRIDE 68       // 64 + 4 pad floats; 272B = 17*16B keeps float4 alignment
#define ROUTE_SCALE 2.5f

__global__ __launch_bounds__(256, 2)
void router_kernel(const float* __restrict__ x,
                   const float* __restrict__ gw,
                   const float* __restrict__ bias,
                   float* __restrict__ out)
{
    __shared__ float xs[TB][XS_STRIDE];
    __shared__ float ws[NE][XS_STRIDE];
    __shared__ float sc[TB][NE + 1];   // sigmoid scores; stride 65 → conflict-free row reads
    __shared__ float bias_lds[NE];
    __shared__ int   hist_lds[NE];

    const int t    = threadIdx.x;
    const int tok0 = blockIdx.x * TB;

    if (t < NE) { bias_lds[t] = bias[t]; hist_lds[t] = 0; }

    const int tt = t & 15;     // token lane 0..15  (tokens tt, tt+16)
    const int ee = t >> 4;     // expert lane 0..15 (experts ee, ee+16, ee+32, ee+48)

    const int lrow  = t >> 4;  // staging row 0..15
    const int lcol4 = t & 15;  // staging float4 column 0..15

    float acc[2][4];
#pragma unroll
    for (int i = 0; i < 2; ++i)
#pragma unroll
        for (int j = 0; j < 4; ++j) acc[i][j] = 0.f;

    for (int dc = 0; dc < DIM; dc += DC) {
        __syncthreads();   // previous compute done before LDS overwrite (also covers init)
        // stage x tile: 32 rows x 64 floats
#pragma unroll
        for (int p = 0; p < TB / 16; ++p) {
            const int r = lrow + 16 * p;
            float4 v = *(const float4*)&x[(size_t)(tok0 + r) * DIM + dc + lcol4 * 4];
            *(float4*)&xs[r][lcol4 * 4] = v;
        }
        // stage gw tile: 64 rows x 64 floats
#pragma unroll
        for (int p = 0; p < NE / 16; ++p) {
            const int r = lrow + 16 * p;
            float4 v = *(const float4*)&gw[(size_t)r * DIM + dc + lcol4 * 4];
            *(float4*)&ws[r][lcol4 * 4] = v;
        }
        __syncthreads();

#pragma unroll
        for (int dq = 0; dq < DC / 4; ++dq) {
            float4 xa[2], wb[4];
#pragma unroll
            for (int i = 0; i < 2; ++i) xa[i] = *(const float4*)&xs[tt + 16 * i][dq * 4];
#pragma unroll
            for (int j = 0; j < 4; ++j) wb[j] = *(const float4*)&ws[ee + 16 * j][dq * 4];
#pragma unroll
            for (int i = 0; i < 2; ++i)
#pragma unroll
                for (int j = 0; j < 4; ++j) {
                    acc[i][j] = fmaf(xa[i].x, wb[j].x, acc[i][j]);
                    acc[i][j] = fmaf(xa[i].y, wb[j].y, acc[i][j]);
                    acc[i][j] = fmaf(xa[i].z, wb[j].z, acc[i][j]);
                    acc[i][j] = fmaf(xa[i].w, wb[j].w, acc[i][j]);
                }
        }
    }

    // sigmoid -> LDS score matrix (each thread writes its own 8 cells)
#pragma unroll
    for (int i = 0; i < 2; ++i)
#pragma unroll
        for (int j = 0; j < 4; ++j) {
            float s = 1.f / (1.f + expf(-acc[i][j]));
            sc[tt + 16 * i][ee + 16 * j] = s;
        }
    __syncthreads();

    // top-8 per token: thread t (< TB) owns token t
    if (t < TB) {
        float topv[TOPK];
        int   topi[TOPK];
        float sum = 0.f;
#pragma unroll
        for (int k = 0; k < TOPK; ++k) {
            float best = -1e30f;
            int   bi   = 0;
            for (int e = 0; e < NE; ++e) {
                float b = sc[t][e] + bias_lds[e];
                if (b > best) { best = b; bi = e; }   // strict > => lowest index wins ties
            }
            float s  = sc[t][bi];
            topv[k]  = s;
            topi[k]  = bi;
            sum     += s;
            sc[t][bi] = -1e30f;   // remove from further rounds
        }
        const float denom = sum + 1e-20f;
        const size_t tok  = (size_t)tok0 + t;
#pragma unroll
        for (int k = 0; k < TOPK; ++k) {
            out[tok * TOPK + k] = (topv[k] / denom) * ROUTE_SCALE;   // match ref rounding order
            out[(size_t)NTOK * TOPK + tok * TOPK + k] = (float)topi[k];
            atomicAdd(&hist_lds[topi[k]], 1);
        }
    }
    __syncthreads();

    if (t < NE) {
        int c = hist_lds[t];
        if (c) atomicAdd(&out[(size_t)NTOK * TOPK * 2 + t], (float)c);
    }
}

extern "C" void kernel_launch(void* const* d_in, const int* in_sizes, int n_in,
                              void* d_out, int out_size, void* d_ws, size_t ws_size,
                              hipStream_t stream)
{
    const float* x    = (const float*)d_in[0];
    const float* gw   = (const float*)d_in[1];
    const float* bias = (const float*)d_in[2];
    float* out = (float*)d_out;

    // histogram region must start at zero every call (atomics accumulate into it)
    hipMemsetAsync(out + (size_t)NTOK * TOPK * 2, 0, NE * sizeof(float), stream);

    router_kernel<<<NTOK / TB, 256, 0, stream>>>(x, gw, bias, out);
}